// Round 2
// 4376.749 us; speedup vs baseline: 2.5651x; 2.5651x over previous
//
#include <hip/hip_runtime.h>
#include <hip/hip_bf16.h>

// Problem dims
#define B_   64
#define S_   256
#define E_   512
#define H_   1024
#define D_   512
#define C_   2
#define G4   4096   // 4*H
#define NB   256    // blocks in persistent recurrence (== block size for flag poll)

typedef __attribute__((ext_vector_type(8))) short short8;   // 8 bf16 (4 VGPRs)
typedef __attribute__((ext_vector_type(4))) float f32x4;

__device__ __forceinline__ float bf2f(unsigned short u) {
    unsigned int x = ((unsigned int)u) << 16;
    return __uint_as_float(x);
}
__device__ __forceinline__ unsigned short f2bf(float f) {
    unsigned int x = __float_as_uint(f);
    unsigned int r = (x + 0x7fffu + ((x >> 16) & 1u)) >> 16;
    return (unsigned short)r;
}

// ---------------------------------------------------------------------------
// Kernel D: detect fp32 (flag=1) vs bf16 (flag=0) float inputs (probe emb).
__global__ void detect_kernel(const unsigned short* __restrict__ emb_u,
                              int* __restrict__ flag)
{
    __shared__ int cnt;
    if (threadIdx.x == 0) cnt = 0;
    __syncthreads();
    int bad = 0;
#pragma unroll
    for (int i = 0; i < 8; ++i) {
        unsigned short u = emb_u[threadIdx.x * 8 + i];
        float a = fabsf(bf2f(u));
        if (!(a < 4.0f)) bad = 1;
        else if (a != 0.0f && a < 1e-20f) bad = 1;
    }
    if (bad) atomicAdd(&cnt, 1);
    __syncthreads();
    if (threadIdx.x == 0) *flag = (cnt > 16) ? 1 : 0;
}

// ---------------------------------------------------------------------------
// Workspace float offsets
#define OFF_WFX   0L          // 2097152  (Wx rows 0..511, fp32 [k][n])
#define OFF_WB    2097152L    // 4194304 floats = 8.4M ushort: MFMA B-frags
                              //   WB[bk][ks][term][lane][8]  (hi=term0, lo=term1)
#define OFF_BIAS  6291456L    // 4096
#define OFF_WD    6295552L    // 524288
#define OFF_DB    6819840L    // 512
#define OFF_WP    6820352L    // 1024
#define OFF_PB    6821376L    // 16 (2 used)
#define OFF_FH    6821392L    // 65536
#define OFF_DEN   6886928L    // 32768
#define OFF_HH    6919696L    // 131072 floats = 4 ushort bufs of 65536:
                              //   A-frag-order h: hiA, loA, hiB, loB
#define OFF_BAR   7050768L    // 512 uints: done[256]@0, flag@400
#define OFF_XPROJ 7051280L    // 67108864

// Kernel P: convert/relayout weights (bf16 hi/lo MFMA B-frag order),
// zero fhT, t=0 h buffers (hiA, loA), done[] flags.
// Items: Wfx 2097152 | WBpairs 4194304 | bias 4096 | Wd 524288 | db 512 |
//        Wp 1024 | pb 2 | fhT 65536 | h-zero 65536 uints | bar 320
#define PREP_TOTAL 6952770
__global__ void prep_kernel(const void* __restrict__ lk,
                            const void* __restrict__ lb,
                            const void* __restrict__ dw,
                            const void* __restrict__ dbm,
                            const void* __restrict__ pw,
                            const void* __restrict__ pbm,
                            const int* __restrict__ flag,
                            float* __restrict__ w)
{
    const bool f32 = (*flag != 0);
    long i = (long)blockIdx.x * 256 + threadIdx.x;
    if (i >= PREP_TOTAL) return;
#define CV(p, j) (f32 ? ((const float*)(p))[j] : bf2f(((const unsigned short*)(p))[j]))
    if (i < 2097152) { w[OFF_WFX + i] = CV(lk, i); return; }  i -= 2097152;
    if (i < 4194304) {
        // B-frag relayout: block bk owns cols c=g*4+jj (n = g*1024 + bk*4+jj).
        // lane l holds B[k = ks*32 + (l>>4)*8 + j][c = l&15], j=0..7.
        int j  = (int)(i & 7);
        int l  = (int)((i >> 3) & 63);
        int ks = (int)((i >> 9) & 31);
        int bk = (int)(i >> 14);
        int c  = l & 15, q = l >> 4;
        int k  = ks * 32 + q * 8 + j;
        int g  = c >> 2, jj = c & 3;
        long src = (long)(512 + k) * G4 + g * H_ + bk * 4 + jj;
        float v = CV(lk, src);
        unsigned short hi = f2bf(v);
        unsigned short lo = f2bf(v - bf2f(hi));
        unsigned short* WBu = (unsigned short*)(w + OFF_WB);
        long base = ((long)(bk * 32 + ks) * 2) * 512 + l * 8 + j;
        WBu[base]       = hi;   // term 0
        WBu[base + 512] = lo;   // term 1
        return;
    }  i -= 4194304;
    if (i < 4096)    { w[OFF_BIAS + i] = CV(lb, i);  return; }  i -= 4096;
    if (i < 524288)  { w[OFF_WD + i]   = CV(dw, i);  return; }  i -= 524288;
    if (i < 512)     { w[OFF_DB + i]   = CV(dbm, i); return; }  i -= 512;
    if (i < 1024)    { w[OFF_WP + i]   = CV(pw, i);  return; }  i -= 1024;
    if (i < 2)       { w[OFF_PB + i]   = CV(pbm, i); return; }  i -= 2;
    if (i < 65536)   { w[OFF_FH + i] = 0.f; return; }  i -= 65536;
    if (i < 65536)   { ((unsigned int*)(w + OFF_HH))[i] = 0u; return; }  i -= 65536;
    if (i < 320)     { ((unsigned int*)(w + OFF_BAR))[i] = 0u; return; }
#undef CV
}

// ---------------------------------------------------------------------------
// Kernel A: xprojT[t][n][b] = sum_e emb[X[b,t]][e] * Wfx[e][n] + bias[n]
__global__ __launch_bounds__(256) void xproj_kernel(
    const int* __restrict__ X,
    const void* __restrict__ emb,
    const int* __restrict__ flag,
    const float* __restrict__ Wfx,
    const float* __restrict__ biasf,
    float* __restrict__ xprojT)
{
    const int t    = blockIdx.y;
    const int cb   = blockIdx.x;
    const int tid  = threadIdx.x;
    const int lane = tid & 63;
    const int wv   = __builtin_amdgcn_readfirstlane(tid >> 6);
    const bool f32 = (*flag != 0);

    __shared__ float embT[128 * 64];
    __shared__ int   rowid[64];

    if (tid < 64) rowid[tid] = X[tid * S_ + t];
    __syncthreads();

    const int n0 = cb * 64 + wv * 16;
    float acc[16];
#pragma unroll
    for (int c = 0; c < 16; ++c) acc[c] = biasf[n0 + c];

    const long myrow = (long)rowid[lane] * E_;

    for (int kc = 0; kc < 4; ++kc) {
        const int k0 = kc * 128;
        if (f32) {
            const float4* src = (const float4*)((const float*)emb + myrow + k0 + wv * 32);
#pragma unroll
            for (int u = 0; u < 8; ++u) {
                float4 v = src[u];
                int kl = wv * 32 + u * 4;
                embT[(kl + 0) * 64 + lane] = v.x;
                embT[(kl + 1) * 64 + lane] = v.y;
                embT[(kl + 2) * 64 + lane] = v.z;
                embT[(kl + 3) * 64 + lane] = v.w;
            }
        } else {
            const uint4* src = (const uint4*)((const unsigned short*)emb + myrow + k0 + wv * 32);
#pragma unroll
            for (int u = 0; u < 4; ++u) {
                uint4 v = src[u];
                int kl = wv * 32 + u * 8;
                embT[(kl + 0) * 64 + lane] = bf2f((unsigned short)(v.x & 0xffff));
                embT[(kl + 1) * 64 + lane] = bf2f((unsigned short)(v.x >> 16));
                embT[(kl + 2) * 64 + lane] = bf2f((unsigned short)(v.y & 0xffff));
                embT[(kl + 3) * 64 + lane] = bf2f((unsigned short)(v.y >> 16));
                embT[(kl + 4) * 64 + lane] = bf2f((unsigned short)(v.z & 0xffff));
                embT[(kl + 5) * 64 + lane] = bf2f((unsigned short)(v.z >> 16));
                embT[(kl + 6) * 64 + lane] = bf2f((unsigned short)(v.w & 0xffff));
                embT[(kl + 7) * 64 + lane] = bf2f((unsigned short)(v.w >> 16));
            }
        }
        __syncthreads();

        const float* wbase = Wfx + (long)k0 * G4 + n0;
#pragma unroll 2
        for (int k = 0; k < 128; ++k) {
            float hv = embT[k * 64 + lane];
            const float* wr = wbase + (long)k * G4;
#pragma unroll
            for (int c = 0; c < 16; ++c) acc[c] += wr[c] * hv;
        }
        __syncthreads();
    }

    float* dst = xprojT + ((long)t * G4 + n0) * 64 + lane;
#pragma unroll
    for (int c = 0; c < 16; ++c) dst[c * 64] = acc[c];
}

// ---------------------------------------------------------------------------
// Flag-array grid barrier, FENCELESS protocol:
// All h-state data movement uses agent-scope (sc-flagged) relaxed atomics
// that write through to / read from the coherent LLC, bypassing the
// non-coherent per-CU L1 and per-XCD L2. Therefore NO buffer_wbl2 /
// buffer_inv cache-maintenance is needed per step (that was ~95% of the
// per-step cost in the fenced version: full-L2 writeback + invalidate
// walks every step for every block). Release ordering: every wave drains
// its own vmcnt to 0 (stores confirmed at the coherence point) BEFORE
// __syncthreads; then one relaxed flag store. Acquire: consumers' h loads
// bypass L1/L2, so data observed at the LLC after the flag is fresh.
// Safe with double-buffered h: write-own-then-poll bounds skew to <=1 step.
// NOTE: h stores are native 32-bit atomic stores (packed pairs) — NO
// sub-dword atomics anywhere (16-bit atomic stores would expand to
// contended global CAS loops).
__device__ __forceinline__ void grid_barrier(unsigned int* done, int t)
{
    // Drain THIS wave's write-through h stores to the coherence point.
    asm volatile("s_waitcnt vmcnt(0)" ::: "memory");
    __syncthreads();   // now every wave's stores are at the LLC
    if (threadIdx.x == 0) {
        __hip_atomic_store(&done[blockIdx.x], (unsigned)(t + 1),
                           __ATOMIC_RELAXED, __HIP_MEMORY_SCOPE_AGENT);
    }
    const unsigned tgt = (unsigned)(t + 1);
    while (!__syncthreads_and(
        (int)(__hip_atomic_load(&done[threadIdx.x], __ATOMIC_RELAXED,
                                __HIP_MEMORY_SCOPE_AGENT) >= tgt))) {
        __builtin_amdgcn_s_sleep(1);
    }
    __syncthreads();   // compiler fence: no hoisting of next step's loads
}

// ---------------------------------------------------------------------------
// LLC-coherent A-frag chunk load: 8 ks-steps of (hi,lo) fragments as
// agent-scope relaxed 8B atomic loads (native global_load_dwordx2 with
// cache-bypass bits; hit LLC). Issued back-to-back with no intervening
// consumption -> all 32 loads in flight.
__device__ __forceinline__ void load_chunk(unsigned long long* buf,
                                           const unsigned short* hiP,
                                           const unsigned short* loP,
                                           int ks0)
{
#pragma unroll
    for (int u = 0; u < 8; ++u) {
        const unsigned short* ph = hiP + (long)(ks0 + u) * 2048;
        const unsigned short* pl = loP + (long)(ks0 + u) * 2048;
        buf[u * 4 + 0] = __hip_atomic_load((const unsigned long long*)ph,
                            __ATOMIC_RELAXED, __HIP_MEMORY_SCOPE_AGENT);
        buf[u * 4 + 1] = __hip_atomic_load((const unsigned long long*)(ph + 4),
                            __ATOMIC_RELAXED, __HIP_MEMORY_SCOPE_AGENT);
        buf[u * 4 + 2] = __hip_atomic_load((const unsigned long long*)pl,
                            __ATOMIC_RELAXED, __HIP_MEMORY_SCOPE_AGENT);
        buf[u * 4 + 3] = __hip_atomic_load((const unsigned long long*)(pl + 4),
                            __ATOMIC_RELAXED, __HIP_MEMORY_SCOPE_AGENT);
    }
}

__device__ __forceinline__ void mfma_chunk(const unsigned long long* buf,
                                           const unsigned short* WBl, int lane,
                                           int ks0,
                                           f32x4& acc0, f32x4& acc1, f32x4& acc2)
{
#pragma unroll
    for (int u = 0; u < 8; ++u) {
        union { unsigned long long q[2]; short8 v; } ch, cl;
        ch.q[0] = buf[u * 4 + 0];
        ch.q[1] = buf[u * 4 + 1];
        cl.q[0] = buf[u * 4 + 2];
        cl.q[1] = buf[u * 4 + 3];
        const int ks = ks0 + u;
        short8 bhi = *(const short8*)(&WBl[(ks * 2 + 0) * 512 + (lane << 3)]);
        short8 blo = *(const short8*)(&WBl[(ks * 2 + 1) * 512 + (lane << 3)]);
        acc0 = __builtin_amdgcn_mfma_f32_16x16x32_bf16(ch.v, bhi, acc0, 0, 0, 0);
        acc1 = __builtin_amdgcn_mfma_f32_16x16x32_bf16(ch.v, blo, acc1, 0, 0, 0);
        acc2 = __builtin_amdgcn_mfma_f32_16x16x32_bf16(cl.v, bhi, acc2, 0, 0, 0);
    }
}

// ---------------------------------------------------------------------------
// Persistent MFMA LSTM recurrence. 256 blocks x 256 thr (4 waves).
// Block bk owns h-dims j0=bk*4..+3 -> 16 gate cols c=g*4+jj.
// Weights: bf16 hi/lo B-frags, LDS-resident (staged once, 64 KB).
// h: bf16 hi/lo in global, A-FRAGMENT ORDER, exchanged through the coherent
// LLC with agent-scope relaxed atomics (no threadfence / no L2 walks).
// h-writes: per-thread hi/lo shorts are exchanged via LDS and emitted as
// native 32-bit packed atomic stores (each block's 4 j-values = two aligned
// dwords per (mt,cc); wave wv stores {hi,lo}[wv>>1], word (wv&1)).
__global__ __launch_bounds__(256) void lstm_persistent(
    unsigned short* __restrict__ hU,     // hiA | loA | hiB | loB (65536 each)
    float* __restrict__ fhT,
    const unsigned short* __restrict__ WBg,
    const float* __restrict__ xprojT,
    const int* __restrict__ seqlen, unsigned int* __restrict__ done)
{
    const int tid  = threadIdx.x;
    const int lane = tid & 63;
    const int wv   = __builtin_amdgcn_readfirstlane(tid >> 6);  // 0..3
    const int bk   = blockIdx.x;

    __shared__ unsigned short WBl[32768];   // 64 KB B-frags [ks][term][lane][8]
    __shared__ float gates[64 * 17];        // [m=b][c] +pad
    __shared__ float cTl[256];              // [jj][b] cell state, LDS-resident
    __shared__ unsigned short hEx[2][256];  // [hi/lo][jj*64+b] exchange

    // stage weight frags (once) + init c
    {
        const uint4* src = (const uint4*)(WBg + (long)bk * 32768);
        uint4* dst = (uint4*)WBl;
#pragma unroll
        for (int u = 0; u < 16; ++u) dst[tid + u * 256] = src[tid + u * 256];
        cTl[tid] = 0.f;
    }
    __syncthreads();

    const int myseq = seqlen[lane];
    const int q = lane >> 4, c = lane & 15;

    unsigned short* hiA = hU;
    unsigned short* loA = hU + 65536;
    unsigned short* hiB = hU + 131072;
    unsigned short* loB = hU + 196608;

    unsigned short *curHi = hiA, *curLo = loA, *nxtHi = hiB, *nxtLo = loB;

    // Block-constant A-frag coords of this block's j-span (j = bk*4 + jj):
    //   wks = j>>5, wq = (j>>3)&3 are constant over jj=0..3; wj8 = (bk&1)*4+jj.
    const int wks = bk >> 3;
    const int wq  = (bk >> 1) & 3;
    // Packed-store role of this thread: word p = wv&1 (wj8 pair 2p,2p+1
    // within the (bk&1)*4 span), sel = wv>>1 (0 = hi buffer, 1 = lo buffer).
    const int pw_ = wv & 1, sel = wv >> 1;
    const long widx = ((((long)wks * 4 + (lane >> 4)) * 4 + wq) * 16
                       + (lane & 15)) * 4 + (bk & 1) * 2 + pw_;

    for (int t = 0; t < S_; ++t) {
        // prefetch xproj for pointwise (thread = (jj=wv, b=lane))
        const long xb = (long)t * G4 + bk * 4 + wv;
        const float xq0 = xprojT[(xb + 0 * H_) * 64 + lane];
        const float xq1 = xprojT[(xb + 1 * H_) * 64 + lane];
        const float xq2 = xprojT[(xb + 2 * H_) * 64 + lane];
        const float xq3 = xprojT[(xb + 3 * H_) * 64 + lane];

        // A-frag loads: wave wv's tile, contiguous 1KB per (hi,lo) pair
        const unsigned short* hiP = curHi + ((long)wv * 64 + lane) * 8;
        const unsigned short* loP = curLo + ((long)wv * 64 + lane) * 8;

        f32x4 acc0 = {0.f, 0.f, 0.f, 0.f};
        f32x4 acc1 = {0.f, 0.f, 0.f, 0.f};
        f32x4 acc2 = {0.f, 0.f, 0.f, 0.f};

        // 2-deep chunk pipeline: keep ~64 LLC loads in flight while MFMAing.
        unsigned long long bufA[32], bufB[32];
        load_chunk(bufA, hiP, loP, 0);
        load_chunk(bufB, hiP, loP, 8);
        mfma_chunk(bufA, WBl, lane, 0,  acc0, acc1, acc2);
        load_chunk(bufA, hiP, loP, 16);
        mfma_chunk(bufB, WBl, lane, 8,  acc0, acc1, acc2);
        load_chunk(bufB, hiP, loP, 24);
        mfma_chunk(bufA, WBl, lane, 16, acc0, acc1, acc2);
        mfma_chunk(bufB, WBl, lane, 24, acc0, acc1, acc2);

        // C tile -> LDS: lane (q,c), reg r holds C[m = wv*16 + q*4 + r][c]
#pragma unroll
        for (int r = 0; r < 4; ++r)
            gates[(wv * 16 + q * 4 + r) * 17 + c] = acc0[r] + acc1[r] + acc2[r];
        __syncthreads();

        // pointwise: thread (jj=wv, b=lane); gate order i,j,f,o
        {
            const int jj = wv, b = lane;
            const float gi = gates[b * 17 +  0 + jj] + xq0;
            const float gj = gates[b * 17 +  4 + jj] + xq1;
            const float gf = gates[b * 17 +  8 + jj] + xq2;
            const float go = gates[b * 17 + 12 + jj] + xq3;

            const float c_old = cTl[jj * 64 + b];
            const float fgate = 1.f / (1.f + expf(-(gf + 1.0f)));  // forget bias
            const float igate = 1.f / (1.f + expf(-gi));
            const float ogate = 1.f / (1.f + expf(-go));
            const float cnew  = c_old * fgate + igate * tanhf(gj);
            const float hnew  = tanhf(cnew) * ogate;
            cTl[jj * 64 + b] = cnew;

            hEx[0][jj * 64 + b] = f2bf(hnew);
            hEx[1][jj * 64 + b] = f2bf(hnew - bf2f(f2bf(hnew)));
            if (t == myseq - 1) fhT[(bk * 4 + jj) * 64 + b] = hnew;
        }
        __syncthreads();

        // packed 32-bit h store: word pw_ of {hi,lo}[sel] for this lane's
        // (mt = lane>>4, cc = lane&15); dwords are the (2p,2p+1) wj8 pair.
        {
            const unsigned lo16 = hEx[sel][(2 * pw_ + 0) * 64 + lane];
            const unsigned hi16 = hEx[sel][(2 * pw_ + 1) * 64 + lane];
            unsigned int* dstw = (unsigned int*)(sel ? nxtLo : nxtHi);
            __hip_atomic_store(dstw + widx, lo16 | (hi16 << 16),
                               __ATOMIC_RELAXED, __HIP_MEMORY_SCOPE_AGENT);
        }

        grid_barrier(done, t);

        unsigned short* s;
        s = curHi; curHi = nxtHi; nxtHi = s;
        s = curLo; curLo = nxtLo; nxtLo = s;
    }
}

// ---------------------------------------------------------------------------
// Kernel C1: denseT[d][b] = relu(fh[b] . dense_w[:,d] + db[d])
__global__ __launch_bounds__(256) void dense_kernel(
    const float* __restrict__ fhT, const float* __restrict__ Wdf,
    const float* __restrict__ dbf, float* __restrict__ denseT)
{
    const int tid  = threadIdx.x;
    const int lane = tid & 63;
    const int wv   = __builtin_amdgcn_readfirstlane(tid >> 6);
    const int d0   = blockIdx.x * 16 + wv * 4;

    float acc[4] = {0.f, 0.f, 0.f, 0.f};
#pragma unroll 4
    for (int k = 0; k < H_; ++k) {
        float v = fhT[k * 64 + lane];
        const float* wr = Wdf + (long)k * D_ + d0;
        acc[0] += wr[0] * v;
        acc[1] += wr[1] * v;
        acc[2] += wr[2] * v;
        acc[3] += wr[3] * v;
    }
#pragma unroll
    for (int c = 0; c < 4; ++c) {
        float z = acc[c] + dbf[d0 + c];
        z = z > 0.f ? z : 0.f;
        denseT[(d0 + c) * 64 + lane] = z;
    }
}

// Kernel C2: logits; output dtype follows detected input dtype.
__global__ void logits_kernel(const float* __restrict__ denseT,
                              const float* __restrict__ Wpf,
                              const float* __restrict__ pbf,
                              const int* __restrict__ flag,
                              void* __restrict__ out)
{
    const int tid  = threadIdx.x;      // 128 threads: 2 waves
    const int lane = tid & 63;
    const int c    = __builtin_amdgcn_readfirstlane(tid >> 6);
    float acc = 0.f;
#pragma unroll 4
    for (int k = 0; k < D_; ++k)
        acc += denseT[k * 64 + lane] * Wpf[k * C_ + c];
    const float r = acc + pbf[c];
    if (*flag != 0) ((float*)out)[lane * C_ + c] = r;
    else            ((unsigned short*)out)[lane * C_ + c] = f2bf(r);
}

// ---------------------------------------------------------------------------
extern "C" void kernel_launch(void* const* d_in, const int* in_sizes, int n_in,
                              void* d_out, int out_size, void* d_ws, size_t ws_size,
                              hipStream_t stream)
{
    // Map inputs by unique flat element counts; fall back to positional.
    const int want[9] = {16384, 64, 25600000, 6291456, 4096, 524288, 512, 1024, 2};
    const void* p[9];
    for (int i = 0; i < 9; ++i) p[i] = d_in[i];
    if (n_in == 9) {
        bool ok = true;
        const void* q[9];
        for (int i = 0; i < 9; ++i) {
            int found = -1;
            for (int j = 0; j < 9; ++j) if (in_sizes[j] == want[i]) { found = j; break; }
            if (found < 0) { ok = false; break; }
            q[i] = d_in[found];
        }
        if (ok) for (int i = 0; i < 9; ++i) p[i] = q[i];
    }
    const int*  X      = (const int*)p[0];
    const int*  seqlen = (const int*)p[1];
    const void* emb    = p[2];
    const void* lk     = p[3];
    const void* lb     = p[4];
    const void* dw     = p[5];
    const void* dbm    = p[6];
    const void* pw     = p[7];
    const void* pbm    = p[8];

    float* w = (float*)d_ws;
    unsigned int* done = (unsigned int*)(w + OFF_BAR);
    int*          flag = (int*)done + 400;   // outside zeroed [0,320) range

    detect_kernel<<<1, 256, 0, stream>>>((const unsigned short*)emb, flag);

    prep_kernel<<<(PREP_TOTAL + 255) / 256, 256, 0, stream>>>(
        lk, lb, dw, dbm, pw, pbm, flag, w);

    xproj_kernel<<<dim3(64, 256), 256, 0, stream>>>(X, emb, flag,
                                                    w + OFF_WFX, w + OFF_BIAS,
                                                    w + OFF_XPROJ);

    lstm_persistent<<<NB, 256, 0, stream>>>((unsigned short*)(w + OFF_HH),
                                            w + OFF_FH,
                                            (const unsigned short*)(w + OFF_WB),
                                            w + OFF_XPROJ,
                                            seqlen, done);

    dense_kernel<<<32, 256, 0, stream>>>(w + OFF_FH, w + OFF_WD,
                                         w + OFF_DB, w + OFF_DEN);
    logits_kernel<<<1, 128, 0, stream>>>(w + OFF_DEN, w + OFF_WP,
                                         w + OFF_PB, flag, d_out);
}

// Round 3
// 4158.640 us; speedup vs baseline: 2.6996x; 1.0524x over previous
//
#include <hip/hip_runtime.h>
#include <hip/hip_bf16.h>

// Problem dims
#define B_   64
#define S_   256
#define E_   512
#define H_   1024
#define D_   512
#define C_   2
#define G4   4096   // 4*H
#define NB   128    // blocks in persistent recurrence

typedef __attribute__((ext_vector_type(8))) short short8;   // 8 bf16 (4 VGPRs)
typedef __attribute__((ext_vector_type(4))) float f32x4;

__device__ __forceinline__ float bf2f(unsigned short u) {
    unsigned int x = ((unsigned int)u) << 16;
    return __uint_as_float(x);
}
__device__ __forceinline__ unsigned short f2bf(float f) {
    unsigned int x = __float_as_uint(f);
    unsigned int r = (x + 0x7fffu + ((x >> 16) & 1u)) >> 16;
    return (unsigned short)r;
}

// ---------------------------------------------------------------------------
// Kernel D: detect fp32 (flag=1) vs bf16 (flag=0) float inputs (probe emb).
__global__ void detect_kernel(const unsigned short* __restrict__ emb_u,
                              int* __restrict__ flag)
{
    __shared__ int cnt;
    if (threadIdx.x == 0) cnt = 0;
    __syncthreads();
    int bad = 0;
#pragma unroll
    for (int i = 0; i < 8; ++i) {
        unsigned short u = emb_u[threadIdx.x * 8 + i];
        float a = fabsf(bf2f(u));
        if (!(a < 4.0f)) bad = 1;
        else if (a != 0.0f && a < 1e-20f) bad = 1;
    }
    if (bad) atomicAdd(&cnt, 1);
    __syncthreads();
    if (threadIdx.x == 0) *flag = (cnt > 16) ? 1 : 0;
}

// ---------------------------------------------------------------------------
// Workspace float offsets
#define OFF_WFX   0L          // 2097152  (Wx rows 0..511, fp32 [k][n])
#define OFF_WB    2097152L    // 4194304 floats = 8.4M ushort: MFMA B-frags
                              //   WB[bk4][ks][term][lane][8]  (hi=term0, lo=term1)
#define OFF_BIAS  6291456L    // 4096
#define OFF_WD    6295552L    // 524288
#define OFF_DB    6819840L    // 512
#define OFF_WP    6820352L    // 1024
#define OFF_PB    6821376L    // 16 (2 used)
#define OFF_FH    6821392L    // 65536
#define OFF_DEN   6886928L    // 32768
#define OFF_HH    6919696L    // 131072 floats = 4 ushort bufs of 65536:
                              //   A-frag-order h: hiA, loA, hiB, loB
#define OFF_BAR   7050768L    // 512 uints: done[128]@0, flag@400
#define OFF_XPROJ 7051280L    // 67108864

// Kernel P: convert/relayout weights (bf16 hi/lo MFMA B-frag order),
// zero fhT, t=0 h buffers (hiA, loA), done[] flags.
#define PREP_TOTAL 6952770
__global__ void prep_kernel(const void* __restrict__ lk,
                            const void* __restrict__ lb,
                            const void* __restrict__ dw,
                            const void* __restrict__ dbm,
                            const void* __restrict__ pw,
                            const void* __restrict__ pbm,
                            const int* __restrict__ flag,
                            float* __restrict__ w)
{
    const bool f32 = (*flag != 0);
    long i = (long)blockIdx.x * 256 + threadIdx.x;
    if (i >= PREP_TOTAL) return;
#define CV(p, j) (f32 ? ((const float*)(p))[j] : bf2f(((const unsigned short*)(p))[j]))
    if (i < 2097152) { w[OFF_WFX + i] = CV(lk, i); return; }  i -= 2097152;
    if (i < 4194304) {
        // B-frag relayout (per 4-j group bk4): cols c=g*4+jj (n = g*1024 + bk4*4+jj).
        // lane l holds B[k = ks*32 + (l>>4)*8 + j][c = l&15], j=0..7.
        int j  = (int)(i & 7);
        int l  = (int)((i >> 3) & 63);
        int ks = (int)((i >> 9) & 31);
        int bk = (int)(i >> 14);
        int c  = l & 15, q = l >> 4;
        int k  = ks * 32 + q * 8 + j;
        int g  = c >> 2, jj = c & 3;
        long src = (long)(512 + k) * G4 + g * H_ + bk * 4 + jj;
        float v = CV(lk, src);
        unsigned short hi = f2bf(v);
        unsigned short lo = f2bf(v - bf2f(hi));
        unsigned short* WBu = (unsigned short*)(w + OFF_WB);
        long base = ((long)(bk * 32 + ks) * 2) * 512 + l * 8 + j;
        WBu[base]       = hi;   // term 0
        WBu[base + 512] = lo;   // term 1
        return;
    }  i -= 4194304;
    if (i < 4096)    { w[OFF_BIAS + i] = CV(lb, i);  return; }  i -= 4096;
    if (i < 524288)  { w[OFF_WD + i]   = CV(dw, i);  return; }  i -= 524288;
    if (i < 512)     { w[OFF_DB + i]   = CV(dbm, i); return; }  i -= 512;
    if (i < 1024)    { w[OFF_WP + i]   = CV(pw, i);  return; }  i -= 1024;
    if (i < 2)       { w[OFF_PB + i]   = CV(pbm, i); return; }  i -= 2;
    if (i < 65536)   { w[OFF_FH + i] = 0.f; return; }  i -= 65536;
    if (i < 65536)   { ((unsigned int*)(w + OFF_HH))[i] = 0u; return; }  i -= 65536;
    if (i < 320)     { ((unsigned int*)(w + OFF_BAR))[i] = 0u; return; }
#undef CV
}

// ---------------------------------------------------------------------------
// Kernel A: xprojT[t][n][b] = sum_e emb[X[b,t]][e] * Wfx[e][n] + bias[n]
__global__ __launch_bounds__(256) void xproj_kernel(
    const int* __restrict__ X,
    const void* __restrict__ emb,
    const int* __restrict__ flag,
    const float* __restrict__ Wfx,
    const float* __restrict__ biasf,
    float* __restrict__ xprojT)
{
    const int t    = blockIdx.y;
    const int cb   = blockIdx.x;
    const int tid  = threadIdx.x;
    const int lane = tid & 63;
    const int wv   = __builtin_amdgcn_readfirstlane(tid >> 6);
    const bool f32 = (*flag != 0);

    __shared__ float embT[128 * 64];
    __shared__ int   rowid[64];

    if (tid < 64) rowid[tid] = X[tid * S_ + t];
    __syncthreads();

    const int n0 = cb * 64 + wv * 16;
    float acc[16];
#pragma unroll
    for (int c = 0; c < 16; ++c) acc[c] = biasf[n0 + c];

    const long myrow = (long)rowid[lane] * E_;

    for (int kc = 0; kc < 4; ++kc) {
        const int k0 = kc * 128;
        if (f32) {
            const float4* src = (const float4*)((const float*)emb + myrow + k0 + wv * 32);
#pragma unroll
            for (int u = 0; u < 8; ++u) {
                float4 v = src[u];
                int kl = wv * 32 + u * 4;
                embT[(kl + 0) * 64 + lane] = v.x;
                embT[(kl + 1) * 64 + lane] = v.y;
                embT[(kl + 2) * 64 + lane] = v.z;
                embT[(kl + 3) * 64 + lane] = v.w;
            }
        } else {
            const uint4* src = (const uint4*)((const unsigned short*)emb + myrow + k0 + wv * 32);
#pragma unroll
            for (int u = 0; u < 4; ++u) {
                uint4 v = src[u];
                int kl = wv * 32 + u * 8;
                embT[(kl + 0) * 64 + lane] = bf2f((unsigned short)(v.x & 0xffff));
                embT[(kl + 1) * 64 + lane] = bf2f((unsigned short)(v.x >> 16));
                embT[(kl + 2) * 64 + lane] = bf2f((unsigned short)(v.y & 0xffff));
                embT[(kl + 3) * 64 + lane] = bf2f((unsigned short)(v.y >> 16));
                embT[(kl + 4) * 64 + lane] = bf2f((unsigned short)(v.z & 0xffff));
                embT[(kl + 5) * 64 + lane] = bf2f((unsigned short)(v.z >> 16));
                embT[(kl + 6) * 64 + lane] = bf2f((unsigned short)(v.w & 0xffff));
                embT[(kl + 7) * 64 + lane] = bf2f((unsigned short)(v.w >> 16));
            }
        }
        __syncthreads();

        const float* wbase = Wfx + (long)k0 * G4 + n0;
#pragma unroll 2
        for (int k = 0; k < 128; ++k) {
            float hv = embT[k * 64 + lane];
            const float* wr = wbase + (long)k * G4;
#pragma unroll
            for (int c = 0; c < 16; ++c) acc[c] += wr[c] * hv;
        }
        __syncthreads();
    }

    float* dst = xprojT + ((long)t * G4 + n0) * 64 + lane;
#pragma unroll
    for (int c = 0; c < 16; ++c) dst[c * 64] = acc[c];
}

// ---------------------------------------------------------------------------
// Flag-array grid barrier, FENCELESS protocol (see round-2 notes):
// h moves through the coherent LLC via agent-scope relaxed atomics (native
// dword stores / dwordx2 loads with cache-bypass bits) -> no per-step
// buffer_wbl2/buffer_inv walks. Release: each wave drains vmcnt to 0 before
// __syncthreads, then one relaxed flag store. Acquire: h loads bypass L1/L2.
// Only wave 0 polls (2 flags per lane, NB=128), other waves park at the
// closing __syncthreads -> 8x less poll traffic on the 4 flag cache lines.
// Double-buffered h bounds skew to <=1 step.
__device__ __forceinline__ void grid_barrier(unsigned int* done, int t)
{
    asm volatile("s_waitcnt vmcnt(0)" ::: "memory");
    __syncthreads();   // all waves' stores are at the LLC
    if (threadIdx.x == 0) {
        __hip_atomic_store(&done[blockIdx.x], (unsigned)(t + 1),
                           __ATOMIC_RELAXED, __HIP_MEMORY_SCOPE_AGENT);
    }
    if (threadIdx.x < 64) {
        const unsigned tgt = (unsigned)(t + 1);
        const int l2 = threadIdx.x * 2;
        for (;;) {
            unsigned a = __hip_atomic_load(&done[l2],     __ATOMIC_RELAXED,
                                           __HIP_MEMORY_SCOPE_AGENT);
            unsigned b = __hip_atomic_load(&done[l2 + 1], __ATOMIC_RELAXED,
                                           __HIP_MEMORY_SCOPE_AGENT);
            if (__all((int)(a >= tgt && b >= tgt))) break;
            __builtin_amdgcn_s_sleep(1);
        }
    }
    __syncthreads();   // releases waves 1..7; no hoisting of next-step loads
}

// ---------------------------------------------------------------------------
// LLC-coherent A-frag chunk load: 8 ks-steps of (hi,lo) fragments as
// agent-scope relaxed 8B atomic loads (bypass L1/L2, hit LLC). Issued
// back-to-back -> all 32 loads in flight.
__device__ __forceinline__ void load_chunk(unsigned long long* buf,
                                           const unsigned short* hiP,
                                           const unsigned short* loP,
                                           int ks0)
{
#pragma unroll
    for (int u = 0; u < 8; ++u) {
        const unsigned short* ph = hiP + (long)(ks0 + u) * 2048;
        const unsigned short* pl = loP + (long)(ks0 + u) * 2048;
        buf[u * 4 + 0] = __hip_atomic_load((const unsigned long long*)ph,
                            __ATOMIC_RELAXED, __HIP_MEMORY_SCOPE_AGENT);
        buf[u * 4 + 1] = __hip_atomic_load((const unsigned long long*)(ph + 4),
                            __ATOMIC_RELAXED, __HIP_MEMORY_SCOPE_AGENT);
        buf[u * 4 + 2] = __hip_atomic_load((const unsigned long long*)pl,
                            __ATOMIC_RELAXED, __HIP_MEMORY_SCOPE_AGENT);
        buf[u * 4 + 3] = __hip_atomic_load((const unsigned long long*)(pl + 4),
                            __ATOMIC_RELAXED, __HIP_MEMORY_SCOPE_AGENT);
    }
}

// MFMA over one 8-ks chunk, both 16-col tiles of this block, 3 hi/lo terms.
__device__ __forceinline__ void mfma_chunk(const unsigned long long* buf,
                                           const unsigned short* WBl, int lane,
                                           int ks0, f32x4 (&acc)[2][3])
{
#pragma unroll
    for (int u = 0; u < 8; ++u) {
        union { unsigned long long q[2]; short8 v; } ch, cl;
        ch.q[0] = buf[u * 4 + 0];
        ch.q[1] = buf[u * 4 + 1];
        cl.q[0] = buf[u * 4 + 2];
        cl.q[1] = buf[u * 4 + 3];
        const int ks = ks0 + u;
#pragma unroll
        for (int ta = 0; ta < 2; ++ta) {
            short8 bhi = *(const short8*)(&WBl[ta * 32768 + (ks * 2 + 0) * 512 + (lane << 3)]);
            short8 blo = *(const short8*)(&WBl[ta * 32768 + (ks * 2 + 1) * 512 + (lane << 3)]);
            acc[ta][0] = __builtin_amdgcn_mfma_f32_16x16x32_bf16(ch.v, bhi, acc[ta][0], 0, 0, 0);
            acc[ta][1] = __builtin_amdgcn_mfma_f32_16x16x32_bf16(ch.v, blo, acc[ta][1], 0, 0, 0);
            acc[ta][2] = __builtin_amdgcn_mfma_f32_16x16x32_bf16(cl.v, bhi, acc[ta][2], 0, 0, 0);
        }
    }
}

// ---------------------------------------------------------------------------
// Persistent MFMA LSTM recurrence. 128 blocks x 512 thr (8 waves).
// Block bk owns h-dims j = bk*8..bk*8+7 -> 32 gate cols (two 16-col MFMA
// tiles = old 4-j frags 2bk and 2bk+1). Waves = 4 m-tiles x 2 k-halves;
// each block reads full h (hi+lo = 256 KB) exactly ONCE per step ->
// chip-wide LLC broadcast traffic halved vs 256-block layout.
// Weights: bf16 hi/lo B-frags, LDS-resident (128 KB).
// K-split partial gate sums land in gates[kh][m][col]; pointwise
// (512 threads = 8 j x 64 b) sums both halves.
__global__ __launch_bounds__(512, 2) void lstm_persistent(
    unsigned short* __restrict__ hU,     // hiA | loA | hiB | loB (65536 each)
    float* __restrict__ fhT,
    const unsigned short* __restrict__ WBg,
    const float* __restrict__ xprojT,
    const int* __restrict__ seqlen, unsigned int* __restrict__ done)
{
    const int tid  = threadIdx.x;
    const int lane = tid & 63;
    const int wv   = __builtin_amdgcn_readfirstlane(tid >> 6);  // 0..7
    const int bk   = blockIdx.x;        // 0..127
    const int mt   = wv & 3;            // m-tile (batch rows mt*16..+15)
    const int kh   = wv >> 2;           // k-half (ks in [kh*16, kh*16+16))

    __shared__ unsigned short WBl[65536];   // 128 KB B-frags (2 tiles)
    __shared__ float gates[2][64][33];      // [kh][m][tile*16+c] partials
    __shared__ float cTl[512];              // [jj][b] cell state
    __shared__ unsigned short hEx[2][512];  // [hi/lo][jj*64+b] exchange

    // stage weight frags (once) + init c
    {
        const uint4* src = (const uint4*)(WBg + (long)bk * 65536);
        uint4* dst = (uint4*)WBl;
#pragma unroll
        for (int u = 0; u < 16; ++u) dst[tid + u * 512] = src[tid + u * 512];
        cTl[tid] = 0.f;
    }
    __syncthreads();

    const int myseq = seqlen[lane];
    const int q = lane >> 4, c = lane & 15;
    const int jj = wv;                  // pointwise j owner: j = bk*8 + jj

    unsigned short* hiA = hU;
    unsigned short* loA = hU + 65536;
    unsigned short* hiB = hU + 131072;
    unsigned short* loB = hU + 196608;
    unsigned short *curHi = hiA, *curLo = loA, *nxtHi = hiB, *nxtLo = loB;

    // Packed h-store role: 512 threads <-> 512 dwords (hi 256 | lo 256).
    // dword for (j-pair 2p..2p+1, b): A-frag ushort idx =
    //   (bk>>2)*2048 + (b>>4)*512 + (bk&3)*128 + (b&15)*8 + jj  (jj = j&7)
    const int sel = tid >> 8;           // 0 = hi buffer, 1 = lo buffer
    const int bb  = (tid & 255) >> 2;   // batch 0..63
    const int pp  = tid & 3;            // j-pair index
    const long widx = (long)(bk >> 2) * 1024 + (bb >> 4) * 256
                    + (bk & 3) * 64 + (bb & 15) * 4 + pp;

    // xproj prefetch (pipelined across the barrier)
    const long xoff = (long)(bk * 8 + jj);
    float xq0, xq1, xq2, xq3;
    {
        xq0 = xprojT[(xoff + 0 * H_) * 64 + lane];
        xq1 = xprojT[(xoff + 1 * H_) * 64 + lane];
        xq2 = xprojT[(xoff + 2 * H_) * 64 + lane];
        xq3 = xprojT[(xoff + 3 * H_) * 64 + lane];
    }

    for (int t = 0; t < S_; ++t) {
        // A-frag loads: m-tile mt, k-half kh; 16 ks x 2KB, LLC-coherent.
        const unsigned short* hiP = curHi + ((long)mt * 64 + lane) * 8;
        const unsigned short* loP = curLo + ((long)mt * 64 + lane) * 8;
        const int ks0 = kh * 16;

        f32x4 acc[2][3];
#pragma unroll
        for (int ta = 0; ta < 2; ++ta)
#pragma unroll
            for (int tm = 0; tm < 3; ++tm) acc[ta][tm] = {0.f, 0.f, 0.f, 0.f};

        unsigned long long bufA[32], bufB[32];
        load_chunk(bufA, hiP, loP, ks0);
        load_chunk(bufB, hiP, loP, ks0 + 8);
        mfma_chunk(bufA, WBl, lane, ks0, acc);
        mfma_chunk(bufB, WBl, lane, ks0 + 8, acc);

        // C tile -> LDS partials: lane (q,c), reg r = C[m=mt*16+q*4+r][tile c]
#pragma unroll
        for (int ta = 0; ta < 2; ++ta)
#pragma unroll
            for (int r = 0; r < 4; ++r)
                gates[kh][mt * 16 + q * 4 + r][ta * 16 + c] =
                    acc[ta][0][r] + acc[ta][1][r] + acc[ta][2][r];
        __syncthreads();

        // pointwise: thread (jj, b=lane); gate g at block-col g*8+jj
        //   -> tile (jj>>2), tile-col g*4+(jj&3); gate order i,j,f,o
        {
            const int b  = lane;
            const int tb = (jj >> 2) * 16 + (jj & 3);
            const float gi = gates[0][b][tb +  0] + gates[1][b][tb +  0] + xq0;
            const float gj = gates[0][b][tb +  4] + gates[1][b][tb +  4] + xq1;
            const float gf = gates[0][b][tb +  8] + gates[1][b][tb +  8] + xq2;
            const float go = gates[0][b][tb + 12] + gates[1][b][tb + 12] + xq3;

            const float c_old = cTl[jj * 64 + b];
            const float fgate = 1.f / (1.f + expf(-(gf + 1.0f)));  // forget bias
            const float igate = 1.f / (1.f + expf(-gi));
            const float ogate = 1.f / (1.f + expf(-go));
            const float cnew  = c_old * fgate + igate * tanhf(gj);
            const float hnew  = tanhf(cnew) * ogate;
            cTl[jj * 64 + b] = cnew;

            const unsigned short hi = f2bf(hnew);
            hEx[0][jj * 64 + b] = hi;
            hEx[1][jj * 64 + b] = f2bf(hnew - bf2f(hi));
            if (t == myseq - 1) fhT[(bk * 8 + jj) * 64 + b] = hnew;
        }
        __syncthreads();

        // packed 32-bit h store (native atomic store, write-through to LLC)
        {
            const unsigned lo16 = hEx[sel][(2 * pp + 0) * 64 + bb];
            const unsigned hi16 = hEx[sel][(2 * pp + 1) * 64 + bb];
            unsigned int* dstw = (unsigned int*)(sel ? nxtLo : nxtHi);
            __hip_atomic_store(dstw + widx, lo16 | (hi16 << 16),
                               __ATOMIC_RELAXED, __HIP_MEMORY_SCOPE_AGENT);
        }

        // prefetch next step's xproj before the barrier (hides under drain+poll)
        {
            const int  t2  = (t + 1 < S_) ? t + 1 : t;
            const long xb2 = (long)t2 * G4 + xoff;
            xq0 = xprojT[(xb2 + 0 * H_) * 64 + lane];
            xq1 = xprojT[(xb2 + 1 * H_) * 64 + lane];
            xq2 = xprojT[(xb2 + 2 * H_) * 64 + lane];
            xq3 = xprojT[(xb2 + 3 * H_) * 64 + lane];
        }

        grid_barrier(done, t);

        unsigned short* s;
        s = curHi; curHi = nxtHi; nxtHi = s;
        s = curLo; curLo = nxtLo; nxtLo = s;
    }
}

// ---------------------------------------------------------------------------
// Kernel C1: denseT[d][b] = relu(fh[b] . dense_w[:,d] + db[d])
__global__ __launch_bounds__(256) void dense_kernel(
    const float* __restrict__ fhT, const float* __restrict__ Wdf,
    const float* __restrict__ dbf, float* __restrict__ denseT)
{
    const int tid  = threadIdx.x;
    const int lane = tid & 63;
    const int wv   = __builtin_amdgcn_readfirstlane(tid >> 6);
    const int d0   = blockIdx.x * 16 + wv * 4;

    float acc[4] = {0.f, 0.f, 0.f, 0.f};
#pragma unroll 4
    for (int k = 0; k < H_; ++k) {
        float v = fhT[k * 64 + lane];
        const float* wr = Wdf + (long)k * D_ + d0;
        acc[0] += wr[0] * v;
        acc[1] += wr[1] * v;
        acc[2] += wr[2] * v;
        acc[3] += wr[3] * v;
    }
#pragma unroll
    for (int c = 0; c < 4; ++c) {
        float z = acc[c] + dbf[d0 + c];
        z = z > 0.f ? z : 0.f;
        denseT[(d0 + c) * 64 + lane] = z;
    }
}

// Kernel C2: logits; output dtype follows detected input dtype.
__global__ void logits_kernel(const float* __restrict__ denseT,
                              const float* __restrict__ Wpf,
                              const float* __restrict__ pbf,
                              const int* __restrict__ flag,
                              void* __restrict__ out)
{
    const int tid  = threadIdx.x;      // 128 threads: 2 waves
    const int lane = tid & 63;
    const int c    = __builtin_amdgcn_readfirstlane(tid >> 6);
    float acc = 0.f;
#pragma unroll 4
    for (int k = 0; k < D_; ++k)
        acc += denseT[k * 64 + lane] * Wpf[k * C_ + c];
    const float r = acc + pbf[c];
    if (*flag != 0) ((float*)out)[lane * C_ + c] = r;
    else            ((unsigned short*)out)[lane * C_ + c] = f2bf(r);
}

// ---------------------------------------------------------------------------
extern "C" void kernel_launch(void* const* d_in, const int* in_sizes, int n_in,
                              void* d_out, int out_size, void* d_ws, size_t ws_size,
                              hipStream_t stream)
{
    // Map inputs by unique flat element counts; fall back to positional.
    const int want[9] = {16384, 64, 25600000, 6291456, 4096, 524288, 512, 1024, 2};
    const void* p[9];
    for (int i = 0; i < 9; ++i) p[i] = d_in[i];
    if (n_in == 9) {
        bool ok = true;
        const void* q[9];
        for (int i = 0; i < 9; ++i) {
            int found = -1;
            for (int j = 0; j < 9; ++j) if (in_sizes[j] == want[i]) { found = j; break; }
            if (found < 0) { ok = false; break; }
            q[i] = d_in[found];
        }
        if (ok) for (int i = 0; i < 9; ++i) p[i] = q[i];
    }
    const int*  X      = (const int*)p[0];
    const int*  seqlen = (const int*)p[1];
    const void* emb    = p[2];
    const void* lk     = p[3];
    const void* lb     = p[4];
    const void* dw     = p[5];
    const void* dbm    = p[6];
    const void* pw     = p[7];
    const void* pbm    = p[8];

    float* w = (float*)d_ws;
    unsigned int* done = (unsigned int*)(w + OFF_BAR);
    int*          flag = (int*)done + 400;   // outside zeroed [0,320) range

    detect_kernel<<<1, 256, 0, stream>>>((const unsigned short*)emb, flag);

    prep_kernel<<<(PREP_TOTAL + 255) / 256, 256, 0, stream>>>(
        lk, lb, dw, dbm, pw, pbm, flag, w);

    xproj_kernel<<<dim3(64, 256), 256, 0, stream>>>(X, emb, flag,
                                                    w + OFF_WFX, w + OFF_BIAS,
                                                    w + OFF_XPROJ);

    lstm_persistent<<<NB, 512, 0, stream>>>((unsigned short*)(w + OFF_HH),
                                            w + OFF_FH,
                                            (const unsigned short*)(w + OFF_WB),
                                            w + OFF_XPROJ,
                                            seqlen, done);

    dense_kernel<<<32, 256, 0, stream>>>(w + OFF_FH, w + OFF_WD,
                                         w + OFF_DB, w + OFF_DEN);
    logits_kernel<<<1, 128, 0, stream>>>(w + OFF_DEN, w + OFF_WP,
                                         w + OFF_PB, flag, d_out);
}

// Round 5
// 3359.357 us; speedup vs baseline: 3.3419x; 1.2379x over previous
//
#include <hip/hip_runtime.h>
#include <hip/hip_bf16.h>

// Problem dims
#define B_   64
#define S_   256
#define E_   512
#define H_   1024
#define D_   512
#define C_   2
#define G4   4096   // 4*H
#define NB   128    // blocks in persistent recurrence

typedef __attribute__((ext_vector_type(8))) short short8;   // 8 bf16 (4 VGPRs)
typedef __attribute__((ext_vector_type(4))) float f32x4;
typedef __attribute__((ext_vector_type(4))) unsigned int u32x4;  // asm-safe 16B

__device__ __forceinline__ float bf2f(unsigned short u) {
    unsigned int x = ((unsigned int)u) << 16;
    return __uint_as_float(x);
}
__device__ __forceinline__ unsigned short f2bf(float f) {
    unsigned int x = __float_as_uint(f);
    unsigned int r = (x + 0x7fffu + ((x >> 16) & 1u)) >> 16;
    return (unsigned short)r;
}

// ---------------------------------------------------------------------------
// Kernel D: detect fp32 (flag=1) vs bf16 (flag=0) float inputs (probe emb).
__global__ void detect_kernel(const unsigned short* __restrict__ emb_u,
                              int* __restrict__ flag)
{
    __shared__ int cnt;
    if (threadIdx.x == 0) cnt = 0;
    __syncthreads();
    int bad = 0;
#pragma unroll
    for (int i = 0; i < 8; ++i) {
        unsigned short u = emb_u[threadIdx.x * 8 + i];
        float a = fabsf(bf2f(u));
        if (!(a < 4.0f)) bad = 1;
        else if (a != 0.0f && a < 1e-20f) bad = 1;
    }
    if (bad) atomicAdd(&cnt, 1);
    __syncthreads();
    if (threadIdx.x == 0) *flag = (cnt > 16) ? 1 : 0;
}

// ---------------------------------------------------------------------------
// Workspace float offsets
#define OFF_WFX   0L          // 2097152  (Wx rows 0..511, fp32 [k][n])
#define OFF_WB    2097152L    // 4194304 floats = 8.4M ushort: MFMA B-frags
#define OFF_BIAS  6291456L    // 4096
#define OFF_WD    6295552L    // 524288
#define OFF_DB    6819840L    // 512
#define OFF_WP    6820352L    // 1024
#define OFF_PB    6821376L    // 16 (2 used)
#define OFF_FH    6821392L    // 65536
#define OFF_DEN   6886928L    // 32768
#define OFF_HH    6919696L    // 131072 floats = 4 ushort bufs of 65536:
                              //   A-frag-order h: hiA, loA, hiB, loB
#define OFF_BAR   7050768L    // 512 uints: done[128]@0, gdone@128+g*32, flag@400
#define OFF_XPROJ 7051280L    // 67108864

// Kernel P: convert/relayout weights (bf16 hi/lo MFMA B-frag order),
// zero fhT, t=0 h buffers, done[]/gdone[] flags (bar uints [0,384)).
#define PREP_TOTAL 6952834
__global__ void prep_kernel(const void* __restrict__ lk,
                            const void* __restrict__ lb,
                            const void* __restrict__ dw,
                            const void* __restrict__ dbm,
                            const void* __restrict__ pw,
                            const void* __restrict__ pbm,
                            const int* __restrict__ flag,
                            float* __restrict__ w)
{
    const bool f32 = (*flag != 0);
    long i = (long)blockIdx.x * 256 + threadIdx.x;
    if (i >= PREP_TOTAL) return;
#define CV(p, j) (f32 ? ((const float*)(p))[j] : bf2f(((const unsigned short*)(p))[j]))
    if (i < 2097152) { w[OFF_WFX + i] = CV(lk, i); return; }  i -= 2097152;
    if (i < 4194304) {
        // B-frag relayout (per 4-j group bk4): cols c=g*4+jj (n = g*1024 + bk4*4+jj).
        // lane l holds B[k = ks*32 + (l>>4)*8 + j][c = l&15], j=0..7.
        int j  = (int)(i & 7);
        int l  = (int)((i >> 3) & 63);
        int ks = (int)((i >> 9) & 31);
        int bk = (int)(i >> 14);
        int c  = l & 15, q = l >> 4;
        int k  = ks * 32 + q * 8 + j;
        int g  = c >> 2, jj = c & 3;
        long src = (long)(512 + k) * G4 + g * H_ + bk * 4 + jj;
        float v = CV(lk, src);
        unsigned short hi = f2bf(v);
        unsigned short lo = f2bf(v - bf2f(hi));
        unsigned short* WBu = (unsigned short*)(w + OFF_WB);
        long base = ((long)(bk * 32 + ks) * 2) * 512 + l * 8 + j;
        WBu[base]       = hi;   // term 0
        WBu[base + 512] = lo;   // term 1
        return;
    }  i -= 4194304;
    if (i < 4096)    { w[OFF_BIAS + i] = CV(lb, i);  return; }  i -= 4096;
    if (i < 524288)  { w[OFF_WD + i]   = CV(dw, i);  return; }  i -= 524288;
    if (i < 512)     { w[OFF_DB + i]   = CV(dbm, i); return; }  i -= 512;
    if (i < 1024)    { w[OFF_WP + i]   = CV(pw, i);  return; }  i -= 1024;
    if (i < 2)       { w[OFF_PB + i]   = CV(pbm, i); return; }  i -= 2;
    if (i < 65536)   { w[OFF_FH + i] = 0.f; return; }  i -= 65536;
    if (i < 65536)   { ((unsigned int*)(w + OFF_HH))[i] = 0u; return; }  i -= 65536;
    if (i < 384)     { ((unsigned int*)(w + OFF_BAR))[i] = 0u; return; }
#undef CV
}

// ---------------------------------------------------------------------------
// Kernel A: xprojT[t][n][b] = sum_e emb[X[b,t]][e] * Wfx[e][n] + bias[n]
__global__ __launch_bounds__(256) void xproj_kernel(
    const int* __restrict__ X,
    const void* __restrict__ emb,
    const int* __restrict__ flag,
    const float* __restrict__ Wfx,
    const float* __restrict__ biasf,
    float* __restrict__ xprojT)
{
    const int t    = blockIdx.y;
    const int cb   = blockIdx.x;
    const int tid  = threadIdx.x;
    const int lane = tid & 63;
    const int wv   = __builtin_amdgcn_readfirstlane(tid >> 6);
    const bool f32 = (*flag != 0);

    __shared__ float embT[128 * 64];
    __shared__ int   rowid[64];

    if (tid < 64) rowid[tid] = X[tid * S_ + t];
    __syncthreads();

    const int n0 = cb * 64 + wv * 16;
    float acc[16];
#pragma unroll
    for (int c = 0; c < 16; ++c) acc[c] = biasf[n0 + c];

    const long myrow = (long)rowid[lane] * E_;

    for (int kc = 0; kc < 4; ++kc) {
        const int k0 = kc * 128;
        if (f32) {
            const float4* src = (const float4*)((const float*)emb + myrow + k0 + wv * 32);
#pragma unroll
            for (int u = 0; u < 8; ++u) {
                float4 v = src[u];
                int kl = wv * 32 + u * 4;
                embT[(kl + 0) * 64 + lane] = v.x;
                embT[(kl + 1) * 64 + lane] = v.y;
                embT[(kl + 2) * 64 + lane] = v.z;
                embT[(kl + 3) * 64 + lane] = v.w;
            }
        } else {
            const uint4* src = (const uint4*)((const unsigned short*)emb + myrow + k0 + wv * 32);
#pragma unroll
            for (int u = 0; u < 4; ++u) {
                uint4 v = src[u];
                int kl = wv * 32 + u * 8;
                embT[(kl + 0) * 64 + lane] = bf2f((unsigned short)(v.x & 0xffff));
                embT[(kl + 1) * 64 + lane] = bf2f((unsigned short)(v.x >> 16));
                embT[(kl + 2) * 64 + lane] = bf2f((unsigned short)(v.y & 0xffff));
                embT[(kl + 3) * 64 + lane] = bf2f((unsigned short)(v.y >> 16));
                embT[(kl + 4) * 64 + lane] = bf2f((unsigned short)(v.z & 0xffff));
                embT[(kl + 5) * 64 + lane] = bf2f((unsigned short)(v.z >> 16));
                embT[(kl + 6) * 64 + lane] = bf2f((unsigned short)(v.w & 0xffff));
                embT[(kl + 7) * 64 + lane] = bf2f((unsigned short)(v.w >> 16));
            }
        }
        __syncthreads();

        const float* wbase = Wfx + (long)k0 * G4 + n0;
#pragma unroll 2
        for (int k = 0; k < 128; ++k) {
            float hv = embT[k * 64 + lane];
            const float* wr = wbase + (long)k * G4;
#pragma unroll
            for (int c = 0; c < 16; ++c) acc[c] += wr[c] * hv;
        }
        __syncthreads();
    }

    float* dst = xprojT + ((long)t * G4 + n0) * 64 + lane;
#pragma unroll
    for (int c = 0; c < 16; ++c) dst[c * 64] = acc[c];
}

// ---------------------------------------------------------------------------
// Persistent MFMA LSTM recurrence. 128 blocks x 512 thr (8 waves).
// Block bk owns h-dims j = bk*8..bk*8+7 -> 32 gate cols (two 16-col tiles).
// Waves = 4 m-tiles x 2 k-halves. Weights LDS-resident (128 KB).
//
// FENCELESS LLC protocol (rounds 2-3, verified): h moves via L1/L2-bypassing
// (sc0 sc1) accesses through the coherent LLC; release = per-wave vmcnt(0)
// drain before __syncthreads, then one relaxed flag store; acquire = bypassing
// loads. No cache-maintenance walks. Double-buffered h bounds skew to <=1 step.
//
// NEW this round:
//  * 16B h loads via asm global_load_dwordx4 sc0 sc1 (ext_vector u32x4
//    operands — struct uint4 is not asm-"v"-compatible) and 16B packed h
//    stores -> half the MALL request count on the data path.
//  * Two-level tree barrier: members store done[bk]; 8 leader blocks poll
//    their group's 16 member flags and set a per-group flag (spread one per
//    cache line at done[128+g*32]); everyone polls the 8 group flags with
//    sleep-paced loops. ~15x less poll traffic on the flag lines -> the
//    release store is no longer stuck behind a congested MALL queue.
//  * xproj prefetch issued AFTER the flag store so the vmcnt(0) release
//    drain doesn't wait for it; its latency hides under the poll.
__global__ __launch_bounds__(512, 2) void lstm_persistent(
    unsigned short* __restrict__ hU,     // hiA | loA | hiB | loB (65536 each)
    float* __restrict__ fhT,
    const unsigned short* __restrict__ WBg,
    const float* __restrict__ xprojT,
    const int* __restrict__ seqlen, unsigned int* __restrict__ done)
{
    const int tid  = threadIdx.x;
    const int lane = tid & 63;
    const int wv   = __builtin_amdgcn_readfirstlane(tid >> 6);  // 0..7
    const int bk   = blockIdx.x;        // 0..127
    const int mt   = wv & 3;            // m-tile (batch rows mt*16..+15)
    const int kh   = wv >> 2;           // k-half (ks in [kh*16, kh*16+16))

    __shared__ unsigned short WBl[65536];   // 128 KB B-frags (2 tiles)
    __shared__ float gates[2][64][33];      // [kh][m][tile*16+c] partials
    __shared__ float cTl[512];              // [jj][b] cell state
    __shared__ unsigned short hEx[2][512];  // [hi/lo][jj*64+b] exchange

    // stage weight frags (once) + init c
    {
        const uint4* src = (const uint4*)(WBg + (long)bk * 65536);
        uint4* dst = (uint4*)WBl;
#pragma unroll
        for (int u = 0; u < 16; ++u) dst[tid + u * 512] = src[tid + u * 512];
        cTl[tid] = 0.f;
    }
    __syncthreads();

    const int myseq = seqlen[lane];
    const int q = lane >> 4, c = lane & 15;
    const int jj = wv;                  // pointwise j owner: j = bk*8 + jj

    unsigned short* hiA = hU;
    unsigned short* loA = hU + 65536;
    unsigned short* hiB = hU + 131072;
    unsigned short* loB = hU + 196608;
    unsigned short *curHi = hiA, *curLo = loA, *nxtHi = hiB, *nxtLo = loB;

    // Packed 16B h-store role: 128 threads (sel = hi/lo, bb = batch) each
    // store one 16B vec = j-pairs 0..3 for (bb, sel).  Dword index:
    //   (bk>>2)*1024 + (bb>>4)*256 + (bk&3)*64 + (bb&15)*4   (16B aligned)
    const int sel = tid >> 6;           // valid for tid<128: 0=hi, 1=lo
    const int bb  = tid & 63;
    const long widx = (long)(bk >> 2) * 1024 + (bb >> 4) * 256
                    + (bk & 3) * 64 + (bb & 15) * 4;

    // xproj prefetch (pipelined across the barrier)
    const long xoff = (long)(bk * 8 + jj);
    float xq0, xq1, xq2, xq3;
    {
        xq0 = xprojT[(xoff + 0 * H_) * 64 + lane];
        xq1 = xprojT[(xoff + 1 * H_) * 64 + lane];
        xq2 = xprojT[(xoff + 2 * H_) * 64 + lane];
        xq3 = xprojT[(xoff + 3 * H_) * 64 + lane];
    }

    for (int t = 0; t < S_; ++t) {
        // ---- A-frag loads: m-tile mt, k-half kh; 32 x 16B, LLC-coherent ----
        const unsigned short* hiP = curHi + ((long)mt * 64 + lane) * 8;
        const unsigned short* loP = curLo + ((long)mt * 64 + lane) * 8;
        const int ks0 = kh * 16;

        u32x4 hb[16], lbv[16];
#pragma unroll
        for (int u = 0; u < 16; ++u) {
            asm volatile("global_load_dwordx4 %0, %1, off sc0 sc1"
                         : "=v"(hb[u])
                         : "v"(hiP + (long)(ks0 + u) * 2048) : "memory");
            asm volatile("global_load_dwordx4 %0, %1, off sc0 sc1"
                         : "=v"(lbv[u])
                         : "v"(loP + (long)(ks0 + u) * 2048) : "memory");
        }
        asm volatile("s_waitcnt vmcnt(0)" ::: "memory");
        __builtin_amdgcn_sched_barrier(0);

        f32x4 acc[2][3];
#pragma unroll
        for (int ta = 0; ta < 2; ++ta)
#pragma unroll
            for (int tm = 0; tm < 3; ++tm) acc[ta][tm] = {0.f, 0.f, 0.f, 0.f};

#pragma unroll
        for (int u = 0; u < 16; ++u) {
            short8 ahi = __builtin_bit_cast(short8, hb[u]);
            short8 alo = __builtin_bit_cast(short8, lbv[u]);
            const int ks = ks0 + u;
#pragma unroll
            for (int ta = 0; ta < 2; ++ta) {
                short8 bhi = *(const short8*)(&WBl[ta * 32768 + (ks * 2 + 0) * 512 + (lane << 3)]);
                short8 blo = *(const short8*)(&WBl[ta * 32768 + (ks * 2 + 1) * 512 + (lane << 3)]);
                acc[ta][0] = __builtin_amdgcn_mfma_f32_16x16x32_bf16(ahi, bhi, acc[ta][0], 0, 0, 0);
                acc[ta][1] = __builtin_amdgcn_mfma_f32_16x16x32_bf16(ahi, blo, acc[ta][1], 0, 0, 0);
                acc[ta][2] = __builtin_amdgcn_mfma_f32_16x16x32_bf16(alo, bhi, acc[ta][2], 0, 0, 0);
            }
        }

        // C tile -> LDS partials: lane (q,c), reg r = C[m=mt*16+q*4+r][tile c]
#pragma unroll
        for (int ta = 0; ta < 2; ++ta)
#pragma unroll
            for (int r = 0; r < 4; ++r)
                gates[kh][mt * 16 + q * 4 + r][ta * 16 + c] =
                    acc[ta][0][r] + acc[ta][1][r] + acc[ta][2][r];
        __syncthreads();

        // pointwise: thread (jj, b=lane); gate g at block-col g*8+jj
        //   -> tile (jj>>2), tile-col g*4+(jj&3); gate order i,j,f,o
        {
            const int b  = lane;
            const int tb = (jj >> 2) * 16 + (jj & 3);
            const float gi = gates[0][b][tb +  0] + gates[1][b][tb +  0] + xq0;
            const float gj = gates[0][b][tb +  4] + gates[1][b][tb +  4] + xq1;
            const float gf = gates[0][b][tb +  8] + gates[1][b][tb +  8] + xq2;
            const float go = gates[0][b][tb + 12] + gates[1][b][tb + 12] + xq3;

            const float c_old = cTl[jj * 64 + b];
            const float fgate = 1.f / (1.f + expf(-(gf + 1.0f)));  // forget bias
            const float igate = 1.f / (1.f + expf(-gi));
            const float ogate = 1.f / (1.f + expf(-go));
            const float cnew  = c_old * fgate + igate * tanhf(gj);
            const float hnew  = tanhf(cnew) * ogate;
            cTl[jj * 64 + b] = cnew;

            const unsigned short hi = f2bf(hnew);
            hEx[0][jj * 64 + b] = hi;
            hEx[1][jj * 64 + b] = f2bf(hnew - bf2f(hi));
            if (t == myseq - 1) fhT[(bk * 8 + jj) * 64 + b] = hnew;
        }
        __syncthreads();

        // ---- packed 16B h store (write-through to LLC) ----
        if (tid < 128) {
            unsigned a0 = hEx[sel][0 * 64 + bb], a1 = hEx[sel][1 * 64 + bb];
            unsigned a2 = hEx[sel][2 * 64 + bb], a3 = hEx[sel][3 * 64 + bb];
            unsigned a4 = hEx[sel][4 * 64 + bb], a5 = hEx[sel][5 * 64 + bb];
            unsigned a6 = hEx[sel][6 * 64 + bb], a7 = hEx[sel][7 * 64 + bb];
            u32x4 v;
            v.x = a0 | (a1 << 16);
            v.y = a2 | (a3 << 16);
            v.z = a4 | (a5 << 16);
            v.w = a6 | (a7 << 16);
            unsigned int* dstw = (unsigned int*)(sel ? nxtLo : nxtHi) + widx;
            asm volatile("global_store_dwordx4 %0, %1, off sc0 sc1"
                         :: "v"(dstw), "v"(v) : "memory");
        }

        // ---- release: drain h stores (xproj prefetch not yet issued) ----
        asm volatile("s_waitcnt vmcnt(0)" ::: "memory");
        __syncthreads();
        const unsigned tgt = (unsigned)(t + 1);
        if (tid == 0)
            __hip_atomic_store(&done[bk], tgt,
                               __ATOMIC_RELAXED, __HIP_MEMORY_SCOPE_AGENT);

        // prefetch next step's xproj (overlaps the poll wait)
        {
            const int  t2  = (t + 1 < S_) ? t + 1 : t;
            const long xb2 = (long)t2 * G4 + xoff;
            xq0 = xprojT[(xb2 + 0 * H_) * 64 + lane];
            xq1 = xprojT[(xb2 + 1 * H_) * 64 + lane];
            xq2 = xprojT[(xb2 + 2 * H_) * 64 + lane];
            xq3 = xprojT[(xb2 + 3 * H_) * 64 + lane];
        }

        // ---- tree poll (wave 0 only) ----
        if (wv == 0) {
            if (bk < 8) {
                // leader of group bk: poll its 16 member flags (hot loop —
                // leaders are the detection critical path)
                const int mi = bk * 16 + (lane & 15);
                while (!__all((int)(__hip_atomic_load(&done[mi],
                        __ATOMIC_RELAXED, __HIP_MEMORY_SCOPE_AGENT) >= tgt))) {
                    __builtin_amdgcn_s_sleep(2);
                }
                if (lane == 0)
                    __hip_atomic_store(&done[128 + bk * 32], tgt,
                                       __ATOMIC_RELAXED, __HIP_MEMORY_SCOPE_AGENT);
            }
            // everyone: poll the 8 group flags (one per cache line)
            const int gi = 128 + (lane & 7) * 32;
            __builtin_amdgcn_s_sleep(4);
            while (!__all((int)(__hip_atomic_load(&done[gi],
                    __ATOMIC_RELAXED, __HIP_MEMORY_SCOPE_AGENT) >= tgt))) {
                __builtin_amdgcn_s_sleep(8);
            }
        }
        __syncthreads();   // releases waves 1..7; no hoisting of next-step loads

        unsigned short* s;
        s = curHi; curHi = nxtHi; nxtHi = s;
        s = curLo; curLo = nxtLo; nxtLo = s;
    }
}

// ---------------------------------------------------------------------------
// Kernel C1: denseT[d][b] = relu(fh[b] . dense_w[:,d] + db[d])
__global__ __launch_bounds__(256) void dense_kernel(
    const float* __restrict__ fhT, const float* __restrict__ Wdf,
    const float* __restrict__ dbf, float* __restrict__ denseT)
{
    const int tid  = threadIdx.x;
    const int lane = tid & 63;
    const int wv   = __builtin_amdgcn_readfirstlane(tid >> 6);
    const int d0   = blockIdx.x * 16 + wv * 4;

    float acc[4] = {0.f, 0.f, 0.f, 0.f};
#pragma unroll 4
    for (int k = 0; k < H_; ++k) {
        float v = fhT[k * 64 + lane];
        const float* wr = Wdf + (long)k * D_ + d0;
        acc[0] += wr[0] * v;
        acc[1] += wr[1] * v;
        acc[2] += wr[2] * v;
        acc[3] += wr[3] * v;
    }
#pragma unroll
    for (int c = 0; c < 4; ++c) {
        float z = acc[c] + dbf[d0 + c];
        z = z > 0.f ? z : 0.f;
        denseT[(d0 + c) * 64 + lane] = z;
    }
}

// Kernel C2: logits; output dtype follows detected input dtype.
__global__ void logits_kernel(const float* __restrict__ denseT,
                              const float* __restrict__ Wpf,
                              const float* __restrict__ pbf,
                              const int* __restrict__ flag,
                              void* __restrict__ out)
{
    const int tid  = threadIdx.x;      // 128 threads: 2 waves
    const int lane = tid & 63;
    const int c    = __builtin_amdgcn_readfirstlane(tid >> 6);
    float acc = 0.f;
#pragma unroll 4
    for (int k = 0; k < D_; ++k)
        acc += denseT[k * 64 + lane] * Wpf[k * C_ + c];
    const float r = acc + pbf[c];
    if (*flag != 0) ((float*)out)[lane * C_ + c] = r;
    else            ((unsigned short*)out)[lane * C_ + c] = f2bf(r);
}

// ---------------------------------------------------------------------------
extern "C" void kernel_launch(void* const* d_in, const int* in_sizes, int n_in,
                              void* d_out, int out_size, void* d_ws, size_t ws_size,
                              hipStream_t stream)
{
    // Map inputs by unique flat element counts; fall back to positional.
    const int want[9] = {16384, 64, 25600000, 6291456, 4096, 524288, 512, 1024, 2};
    const void* p[9];
    for (int i = 0; i < 9; ++i) p[i] = d_in[i];
    if (n_in == 9) {
        bool ok = true;
        const void* q[9];
        for (int i = 0; i < 9; ++i) {
            int found = -1;
            for (int j = 0; j < 9; ++j) if (in_sizes[j] == want[i]) { found = j; break; }
            if (found < 0) { ok = false; break; }
            q[i] = d_in[found];
        }
        if (ok) for (int i = 0; i < 9; ++i) p[i] = q[i];
    }
    const int*  X      = (const int*)p[0];
    const int*  seqlen = (const int*)p[1];
    const void* emb    = p[2];
    const void* lk     = p[3];
    const void* lb     = p[4];
    const void* dw     = p[5];
    const void* dbm    = p[6];
    const void* pw     = p[7];
    const void* pbm    = p[8];

    float* w = (float*)d_ws;
    unsigned int* done = (unsigned int*)(w + OFF_BAR);
    int*          flag = (int*)done + 400;   // outside zeroed [0,384) range

    detect_kernel<<<1, 256, 0, stream>>>((const unsigned short*)emb, flag);

    prep_kernel<<<(PREP_TOTAL + 255) / 256, 256, 0, stream>>>(
        lk, lb, dw, dbm, pw, pbm, flag, w);

    xproj_kernel<<<dim3(64, 256), 256, 0, stream>>>(X, emb, flag,
                                                    w + OFF_WFX, w + OFF_BIAS,
                                                    w + OFF_XPROJ);

    lstm_persistent<<<NB, 512, 0, stream>>>((unsigned short*)(w + OFF_HH),
                                            w + OFF_FH,
                                            (const unsigned short*)(w + OFF_WB),
                                            w + OFF_XPROJ,
                                            seqlen, done);

    dense_kernel<<<32, 256, 0, stream>>>(w + OFF_FH, w + OFF_WD,
                                         w + OFF_DB, w + OFF_DEN);
    logits_kernel<<<1, 128, 0, stream>>>(w + OFF_DEN, w + OFF_WP,
                                         w + OFF_PB, flag, d_out);
}